// Round 1
// 224.194 us; speedup vs baseline: 1.1730x; 1.1730x over previous
//
#include <hip/hip_runtime.h>
#include <math.h>

#define N_NODES 100000
#define N_EDGES 1000000
#define IN_DIM  128
#define OUT_DIM 64
#define NEG     0.2f

#define SCAN_BLOCKS 391   // ceil(100000/256)
#define EDGE_BLOCKS 3907  // ceil(1000000/256): one edge per thread

// ---------------------------------------------------------------------------
// K1 (MFMA rewrite): Wh = h @ W^T + b via bf16x2 split-precision MFMA.
//   h = h_hi + h_lo, W = W_hi + W_lo (bf16 truncation + bf16 residual);
//   Wh ~= h_hi W_hi + h_hi W_lo + h_lo W_hi  (3 passes, rel err ~2^-16 —
//   output absmax impact ~1e-8, under the fp32 baseline's 2.4e-7).
// Block = 256 thr / 4 waves, 128 nodes/block. Wave = 32 nodes x 64 dims,
// K=128 (m=2 M-frags, nb=4 N-frags, ks=4 K-steps, 96 MFMAs/wave).
// W converted once per block into frag-ordered LDS (16B/lane stride-1 ->
// conflict-free ds_read_b128). A-frags load straight from global (each h
// row owned by exactly one wave; 4 lanes cover each 128B line).
// Epilogue: scores via 16-lane shfl_xor reduce; Wh via LDS transpose
// (reuses W LDS region) -> coalesced float4 stores. LDS 34.8KB -> 3 blk/CU.
// ---------------------------------------------------------------------------
typedef __attribute__((ext_vector_type(8))) short short8;   // 8 bf16 = 4 VGPR
typedef __attribute__((ext_vector_type(4))) float f32x4;

#define MFMA(A, B, C) __builtin_amdgcn_mfma_f32_16x16x32_bf16(A, B, C, 0, 0, 0)

union U16 { unsigned u[4]; short8 s; };

// split 8 fp32 -> bf16 hi (truncate) + bf16 lo (truncated residual).
// Truncation (not RNE) is fine: residual captured to 2^-16 rel overall.
__device__ __forceinline__ void split8(const float* x, short8& hi, short8& lo) {
    U16 H, L;
#pragma unroll
    for (int i = 0; i < 4; ++i) {
        float a = x[2 * i], b = x[2 * i + 1];
        unsigned ua = __float_as_uint(a), ub = __float_as_uint(b);
        unsigned ha = ua & 0xffff0000u, hb = ub & 0xffff0000u;
        H.u[i] = (ua >> 16) | hb;
        float la = a - __uint_as_float(ha);     // exact (low mantissa bits)
        float lb = b - __uint_as_float(hb);
        L.u[i] = (__float_as_uint(la) >> 16) | (__float_as_uint(lb) & 0xffff0000u);
    }
    hi = H.s; lo = L.s;
}

__global__ __launch_bounds__(256, 3) void k1_mfma(
    const float* __restrict__ h, const float* __restrict__ W,
    const float* __restrict__ Wb, const float* __restrict__ aw,
    float* __restrict__ Wh, float* __restrict__ s_src, float* __restrict__ s_tgt)
{
    // 34816 B: staging (wfh 16K | wfl 16K) then reused as tr[128][68] f32
    __shared__ float4 smem4[2176];
    unsigned short* wfh = (unsigned short*)smem4;
    unsigned short* wfl = wfh + 8192;

    const int tid  = threadIdx.x;
    const int lane = tid & 63, w = tid >> 6;
    const int c = lane & 15, g = lane >> 4;
    const int n0 = blockIdx.x * 128;

    // ---- stage W as bf16 hi/lo in frag order: unit U = (nb*4+ks)*64 + lane,
    // holding W[16nb + (l&15)][32ks + 8(l>>4) .. +8]. 1024 units, 4/thread.
#pragma unroll
    for (int it = 0; it < 4; ++it) {
        int U = tid + 256 * it;                 // 0..1023
        int pos = U >> 6, l = U & 63;
        int nb = pos >> 2, ks = pos & 3;
        int r  = 16 * nb + (l & 15);
        int k0 = 32 * ks + 8 * (l >> 4);
        float a[8];
        *(float4*)&a[0] = *(const float4*)(W + r * IN_DIM + k0);
        *(float4*)&a[4] = *(const float4*)(W + r * IN_DIM + k0 + 4);
        short8 hi, lo; split8(a, hi, lo);
        *(short8*)(wfh + (size_t)U * 8) = hi;   // stride-1 b128 writes
        *(short8*)(wfl + (size_t)U * 8) = lo;
    }
    __syncthreads();

    // ---- A row pointers (tail blocks clamp: junk rows computed, never stored)
    const int na0 = n0 + 32 * w + c;
    const float* hp0 = h + (size_t)min(na0, N_NODES - 1) * IN_DIM + 8 * g;
    const float* hp1 = h + (size_t)min(na0 + 16, N_NODES - 1) * IN_DIM + 8 * g;

    f32x4 acc[2][4];
    {
        f32x4 z = {0.f, 0.f, 0.f, 0.f};
#pragma unroll
        for (int m = 0; m < 2; ++m)
#pragma unroll
            for (int nb = 0; nb < 4; ++nb) acc[m][nb] = z;
    }

#pragma unroll 2
    for (int ks = 0; ks < 4; ++ks) {
        short8 bh[4], bl[4];
#pragma unroll
        for (int nb = 0; nb < 4; ++nb) {
            int u = ((nb * 4 + ks) * 64 + lane) * 8;
            bh[nb] = *(const short8*)(wfh + u);
            bl[nb] = *(const short8*)(wfl + u);
        }
        float am[8];
        short8 ah, al;
        *(float4*)&am[0] = *(const float4*)(hp0 + 32 * ks);
        *(float4*)&am[4] = *(const float4*)(hp0 + 32 * ks + 4);
        split8(am, ah, al);
#pragma unroll
        for (int nb = 0; nb < 4; ++nb) {
            acc[0][nb] = MFMA(ah, bh[nb], acc[0][nb]);
            acc[0][nb] = MFMA(ah, bl[nb], acc[0][nb]);
            acc[0][nb] = MFMA(al, bh[nb], acc[0][nb]);
        }
        *(float4*)&am[0] = *(const float4*)(hp1 + 32 * ks);
        *(float4*)&am[4] = *(const float4*)(hp1 + 32 * ks + 4);
        split8(am, ah, al);
#pragma unroll
        for (int nb = 0; nb < 4; ++nb) {
            acc[1][nb] = MFMA(ah, bh[nb], acc[1][nb]);
            acc[1][nb] = MFMA(ah, bl[nb], acc[1][nb]);
            acc[1][nb] = MFMA(al, bh[nb], acc[1][nb]);
        }
    }

    // ---- epilogue: bias + score dot-products.
    // D-frag: lane holds Wh[32w + 16m + 4g + r][16nb + c], r = 0..3.
    float wb[4], w1[4], w2[4];
#pragma unroll
    for (int nb = 0; nb < 4; ++nb) {
        wb[nb] = Wb[16 * nb + c];
        w1[nb] = aw[16 * nb + c];
        w2[nb] = aw[OUT_DIM + 16 * nb + c];
    }
#pragma unroll
    for (int m = 0; m < 2; ++m)
#pragma unroll
        for (int r = 0; r < 4; ++r) {
            float s1 = 0.f, s2 = 0.f;
#pragma unroll
            for (int nb = 0; nb < 4; ++nb) {
                float v = acc[m][nb][r] + wb[nb];
                acc[m][nb][r] = v;
                s1 = fmaf(v, w1[nb], s1);
                s2 = fmaf(v, w2[nb], s2);
            }
            // reduce over the 16 dim-lanes of this node (masks stay in-group)
#pragma unroll
            for (int mk = 1; mk < 16; mk <<= 1) {
                s1 += __shfl_xor(s1, mk);
                s2 += __shfl_xor(s2, mk);
            }
            if (c == 0) {
                int node = n0 + 32 * w + 16 * m + 4 * g + r;
                if (node < N_NODES) { s_src[node] = s1; s_tgt[node] = s2; }
            }
        }

    __syncthreads();                 // all LDS W reads done; reuse as tr
    float* tr = (float*)smem4;       // tr[128][68]: 2-way banks on writes/reads
#pragma unroll
    for (int m = 0; m < 2; ++m)
#pragma unroll
        for (int nb = 0; nb < 4; ++nb)
#pragma unroll
            for (int r = 0; r < 4; ++r)
                tr[(32 * w + 16 * m + 4 * g + r) * 68 + 16 * nb + c] = acc[m][nb][r];
    __syncthreads();

    // coalesced Wh store: 2048 float4, 8/thread
#pragma unroll
    for (int j = 0; j < 8; ++j) {
        int idx = tid + 256 * j;              // 0..2047
        int nloc = idx >> 4, d4 = idx & 15;
        int node = n0 + nloc;
        if (node < N_NODES)
            ((float4*)Wh)[(size_t)node * 16 + d4] =
                *(const float4*)&tr[nloc * 68 + d4 * 4];
    }
}

// ---------------------------------------------------------------------------
// K2 (fused): one edge pass: deg histogram (capturing the returned RANK =
// CSR slot), ex = exp(leaky(l)) stored linearly, block-partial sums to
// bsum[] (plain store — R7's single-address atomicAdd(gsum) serialized 3907
// RMWs and stalled block retirement: occ 59% / VALU 2% / 70µs).
// No max-subtraction: logits bounded (~|12|), exp can't overflow fp32,
// softmax is shift-invariant.
// ---------------------------------------------------------------------------
__global__ __launch_bounds__(256) void k2_fused(
    const int* __restrict__ ei, const float* __restrict__ s_src,
    const float* __restrict__ s_tgt, const float* __restrict__ ab,
    unsigned* __restrict__ deg, unsigned* __restrict__ rank,
    float* __restrict__ exv, float* __restrict__ bsum)
{
    const float ab0 = ab[0];
    float lsum = 0.f;
    const int e = blockIdx.x * blockDim.x + threadIdx.x;
    if (e < N_EDGES) {
        int s = ei[e], t = ei[N_EDGES + e];
        float x = s_src[s] + s_tgt[t] + ab0;
        float l = x > 0.f ? x : NEG * x;
        float ex = __expf(l);
        exv[e] = ex;
        lsum = ex;
        rank[e] = atomicAdd(&deg[t], 1u);   // returned old count = CSR rank
    }
#pragma unroll
    for (int off = 32; off; off >>= 1) lsum += __shfl_xor(lsum, off);
    __shared__ float ssum[4];
    if ((threadIdx.x & 63) == 0) ssum[threadIdx.x >> 6] = lsum;
    __syncthreads();
    if (threadIdx.x == 0)
        bsum[blockIdx.x] = ssum[0] + ssum[1] + ssum[2] + ssum[3];
}

// ---------------------------------------------------------------------------
// Scan (3 kernels): exclusive prefix sum of deg[100000] -> row[].
// k_scan2 additionally reduces bsum[] -> gsum (free ride on the single-block
// dispatch; removes the serialized gsum atomic entirely).
// ---------------------------------------------------------------------------
__global__ __launch_bounds__(256) void k_scan1(
    const unsigned* __restrict__ deg, unsigned* __restrict__ psum)
{
    const int i = blockIdx.x * 256 + threadIdx.x;
    unsigned v = (i < N_NODES) ? deg[i] : 0u;
    unsigned w = v;
#pragma unroll
    for (int off = 32; off; off >>= 1) w += __shfl_xor(w, off);
    __shared__ unsigned ss[4];
    if ((threadIdx.x & 63) == 0) ss[threadIdx.x >> 6] = w;
    __syncthreads();
    if (threadIdx.x == 0) psum[blockIdx.x] = ss[0] + ss[1] + ss[2] + ss[3];
}

__global__ __launch_bounds__(512) void k_scan2(
    const unsigned* __restrict__ psum, unsigned* __restrict__ poff,
    const float* __restrict__ bsum, float* __restrict__ gsum)
{
    __shared__ unsigned sc[512];
    __shared__ float    sf[8];
    const int t = threadIdx.x;

    // part 1: exclusive scan of psum[SCAN_BLOCKS]
    unsigned v = (t < SCAN_BLOCKS) ? psum[t] : 0u;
    sc[t] = v;
    __syncthreads();
    for (int off = 1; off < 512; off <<= 1) {
        unsigned u = (t >= off) ? sc[t - off] : 0u;
        __syncthreads();
        sc[t] += u;
        __syncthreads();
    }
    if (t < SCAN_BLOCKS) poff[t] = sc[t] - v;   // exclusive

    // part 2: reduce bsum[EDGE_BLOCKS] -> gsum
    float s = 0.f;
    for (int i = t; i < EDGE_BLOCKS; i += 512) s += bsum[i];
#pragma unroll
    for (int off = 32; off; off >>= 1) s += __shfl_xor(s, off);
    if ((t & 63) == 0) sf[t >> 6] = s;
    __syncthreads();
    if (t == 0) {
        float tot = 0.f;
#pragma unroll
        for (int i = 0; i < 8; ++i) tot += sf[i];
        gsum[0] = tot;
    }
}

__global__ __launch_bounds__(256) void k_scan3(
    const unsigned* __restrict__ deg, const unsigned* __restrict__ poff,
    unsigned* __restrict__ row)
{
    __shared__ unsigned sc[256];
    const int t = threadIdx.x;
    const int i = blockIdx.x * 256 + t;
    unsigned v = (i < N_NODES) ? deg[i] : 0u;
    sc[t] = v;
    __syncthreads();
    for (int off = 1; off < 256; off <<= 1) {
        unsigned u = (t >= off) ? sc[t - off] : 0u;
        __syncthreads();
        sc[t] += u;
        __syncthreads();
    }
    unsigned r = poff[blockIdx.x] + sc[t] - v;   // exclusive
    if (i < N_NODES) row[i] = r;
    if (i == 0) row[N_NODES] = N_EDGES;
}

// ---------------------------------------------------------------------------
// K3: bin fill, NO atomics: pos = row[t] + rank[e]; scatter write is
// fire-and-forget. One edge per thread.
// ---------------------------------------------------------------------------
__global__ __launch_bounds__(256) void k3_fill(
    const int* __restrict__ ei, const float* __restrict__ exv,
    const unsigned* __restrict__ rank, const unsigned* __restrict__ row,
    int2* __restrict__ bin)
{
    const int e = blockIdx.x * blockDim.x + threadIdx.x;
    if (e >= N_EDGES) return;
    int t = ei[N_EDGES + e];
    unsigned pos = row[t] + rank[e];
    bin[pos] = make_int2(ei[e], __float_as_int(exv[e]));
}

// ---------------------------------------------------------------------------
// K4: gather — wave per tgt node, lane = dim. Bin chunk loaded coalesced
// (8B/lane), entries broadcast via shfl. 4-way ILP: 4 independent gathers +
// 4 accumulators per step. One plain store per node, leaky fused, no atomics.
// ---------------------------------------------------------------------------
__global__ __launch_bounds__(256) void k_gather(
    const unsigned* __restrict__ row, const int2* __restrict__ bin,
    const float* __restrict__ gsum, const float* __restrict__ Wh,
    float* __restrict__ out)
{
    const int lane = threadIdx.x & 63;
    const int t = blockIdx.x * 4 + (threadIdx.x >> 6);
    if (t >= N_NODES) return;
    const unsigned beg = row[t], end = row[t + 1];
    float a0 = 0.f, a1 = 0.f, a2 = 0.f, a3 = 0.f;
    for (unsigned base = beg; base < end; base += 64) {
        const int cnt = (int)min(64u, end - base);
        int2 p = make_int2(0, 0);
        if (lane < cnt) p = bin[base + lane];      // coalesced 8B/lane
        int j = 0;
        for (; j + 4 <= cnt; j += 4) {
            int   s0 = __shfl(p.x, j);     float w0 = __int_as_float(__shfl(p.y, j));
            int   s1 = __shfl(p.x, j + 1); float w1 = __int_as_float(__shfl(p.y, j + 1));
            int   s2 = __shfl(p.x, j + 2); float w2 = __int_as_float(__shfl(p.y, j + 2));
            int   s3 = __shfl(p.x, j + 3); float w3 = __int_as_float(__shfl(p.y, j + 3));
            float v0 = Wh[(size_t)s0 * OUT_DIM + lane];
            float v1 = Wh[(size_t)s1 * OUT_DIM + lane];
            float v2 = Wh[(size_t)s2 * OUT_DIM + lane];
            float v3 = Wh[(size_t)s3 * OUT_DIM + lane];
            a0 = fmaf(w0, v0, a0);
            a1 = fmaf(w1, v1, a1);
            a2 = fmaf(w2, v2, a2);
            a3 = fmaf(w3, v3, a3);
        }
        for (; j < cnt; ++j) {
            int   s = __shfl(p.x, j);
            float w = __int_as_float(__shfl(p.y, j));
            a0 = fmaf(w, Wh[(size_t)s * OUT_DIM + lane], a0);
        }
    }
    float v = ((a0 + a1) + (a2 + a3)) * (1.0f / gsum[0]);
    out[(size_t)t * OUT_DIM + lane] = v > 0.f ? v : NEG * v;
}

extern "C" void kernel_launch(void* const* d_in, const int* in_sizes, int n_in,
                              void* d_out, int out_size, void* d_ws, size_t ws_size,
                              hipStream_t stream)
{
    const float* h  = (const float*)d_in[0];
    const float* W  = (const float*)d_in[1];
    const float* Wb = (const float*)d_in[2];
    const float* aw = (const float*)d_in[3];
    const float* ab = (const float*)d_in[4];
    const int*   ei = (const int*)d_in[5];

    // ws layout: Wh[N*64] f32 | s_src[N] | s_tgt[N] | deg[N] u32 | row[N+1] u32
    //          | psum[512] | poff[512] | bin[E] int2 | exv[E] f32
    //          | rank[E] u32 | bsum[4096] f32 | gsum f32
    float* ws      = (float*)d_ws;
    float* Wh      = ws;
    float* s_src   = Wh + (size_t)N_NODES * OUT_DIM;
    float* s_tgt   = s_src + N_NODES;
    unsigned* deg    = (unsigned*)(s_tgt + N_NODES);
    unsigned* row    = deg + N_NODES;
    unsigned* psum   = row + N_NODES + 1;
    unsigned* poff   = psum + 512;
    int2*     bin    = (int2*)(poff + 512);
    float*    exv    = (float*)(bin + N_EDGES);
    unsigned* rank   = (unsigned*)(exv + N_EDGES);
    float*    bsum   = (float*)(rank + N_EDGES);
    float*    gsum   = bsum + 4096;

    float* out = (float*)d_out;

    hipMemsetAsync((void*)deg, 0, N_NODES * sizeof(unsigned), stream);

    k1_mfma<<<(N_NODES + 127) / 128, 256, 0, stream>>>(h, W, Wb, aw, Wh, s_src, s_tgt);
    k2_fused<<<EDGE_BLOCKS, 256, 0, stream>>>(ei, s_src, s_tgt, ab, deg, rank,
                                              exv, bsum);
    k_scan1<<<SCAN_BLOCKS, 256, 0, stream>>>(deg, psum);
    k_scan2<<<1, 512, 0, stream>>>(psum, poff, bsum, gsum);
    k_scan3<<<SCAN_BLOCKS, 256, 0, stream>>>(deg, poff, row);
    k3_fill<<<EDGE_BLOCKS, 256, 0, stream>>>(ei, exv, rank, row, bin);
    k_gather<<<(N_NODES + 3) / 4, 256, 0, stream>>>(row, bin, gsum, Wh, out);
}